// Round 1
// baseline (756.636 us; speedup 1.0000x reference)
//
#include <hip/hip_runtime.h>
#include <math.h>

// Problem constants (fixed by reference)
#define BATCH 2
#define CIN   256   // x channels
#define COUT  256   // dcn out channels
#define COFF  256   // offset_feat channels
#define HH    64
#define WW    64
#define HWPIX 4096
#define KK    9     // 3x3
#define CKTOT 2304  // CIN*KK

// ---------------------------------------------------------------------------
// Kernel A: om = conv3x3(offset_feat, w_offset_mask) + b_offset_mask
// om: [B][27][64][64] fp32 into workspace
// ---------------------------------------------------------------------------
__global__ __launch_bounds__(256) void conv_om_kernel(
    const float* __restrict__ feat,   // [2][256][4096]
    const float* __restrict__ wom,    // [27][256][3][3]
    const float* __restrict__ bom,    // [27]
    float* __restrict__ om)           // [2][27][4096]
{
    int gid = blockIdx.x * 256 + threadIdx.x;   // 0 .. 2*27*4096-1
    int p  = gid & 4095;
    int bc = gid >> 12;          // 0..53
    int co = bc % 27;
    int b  = bc / 27;
    int y = p >> 6, x = p & 63;

    float acc = bom[co];
    const float* fb   = feat + (size_t)b * COFF * HWPIX;
    const float* wrow = wom  + (size_t)co * CKTOT;

    for (int c = 0; c < COFF; ++c) {
        const float* fc = fb + c * HWPIX;
        const float* wc = wrow + c * 9;
#pragma unroll
        for (int ky = 0; ky < 3; ++ky) {
            int yy = y + ky - 1;
            if ((unsigned)yy >= 64u) continue;
#pragma unroll
            for (int kx = 0; kx < 3; ++kx) {
                int xx = x + kx - 1;
                if ((unsigned)xx >= 64u) continue;
                acc += fc[yy * 64 + xx] * wc[ky * 3 + kx];
            }
        }
    }
    om[gid] = acc;
}

// ---------------------------------------------------------------------------
// Kernel T: transpose w_dcn [256][2304] -> wT [2304][256]
// ---------------------------------------------------------------------------
__global__ __launch_bounds__(256) void transpose_w_kernel(
    const float* __restrict__ wdcn,   // [256][2304]
    float* __restrict__ wT)           // [2304][256]
{
    int gid = blockIdx.x * 256 + threadIdx.x;   // 0 .. 589823
    int ck = gid >> 8;
    int co = gid & 255;
    wT[gid] = wdcn[(size_t)co * CKTOT + ck];
}

// ---------------------------------------------------------------------------
// Kernel B: fused deformable sampling + GEMM
// Each block: one batch b, one row y (64 px), one 64-wide co tile.
// K-loop over 32 chunks of 8 channels (72 ck values per chunk):
//   stage sampled columns (72 x 64) and weights (72 x 64) in LDS, FMA.
// ---------------------------------------------------------------------------
__global__ __launch_bounds__(256) void dcn_fused_kernel(
    const float* __restrict__ xin,    // [2][256][4096]
    const float* __restrict__ om,     // [2][27][4096]
    const float* __restrict__ wT,     // [2304][256]
    const float* __restrict__ bdcn,   // [256]
    float* __restrict__ out)          // [2][256][4096]
{
    const int tid = threadIdx.x;
    const int y       = blockIdx.x;        // 0..63
    const int co_base = blockIdx.y * 64;   // 0,64,128,192
    const int b       = blockIdx.z;        // 0..1

    __shared__ float s_ly[9 * 64], s_lx[9 * 64], s_m[9 * 64];
    __shared__ int   s_y0[9 * 64], s_x0[9 * 64];
    __shared__ float s_col[72][64];
    __shared__ float s_w[72][64];

    // ---- prologue: per-(k,px) sampling coordinates from om -----------------
    for (int idx = tid; idx < 9 * 64; idx += 256) {
        int k  = idx >> 6;     // 0..8
        int xc = idx & 63;
        int p  = y * 64 + xc;
        const float* omb = om + ((size_t)b * 27) * HWPIX;
        float dy = omb[(2 * k) * HWPIX + p];
        float dx = omb[(2 * k + 1) * HWPIX + p];
        float mm = omb[(18 + k) * HWPIX + p];
        float ys = (float)(y - 1 + (k / 3)) + dy;
        float xs = (float)(xc - 1 + (k % 3)) + dx;
        float y0f = floorf(ys);
        float x0f = floorf(xs);
        s_y0[idx] = (int)y0f;
        s_x0[idx] = (int)x0f;
        s_ly[idx] = ys - y0f;
        s_lx[idx] = xs - x0f;
        s_m[idx]  = 1.0f / (1.0f + expf(-mm));
    }
    __syncthreads();

    const int tx = tid & 15;   // px group: px = tx*4 .. tx*4+3
    const int ty = tid >> 4;   // co group: co = co_base + ty*4 .. +3

    float acc[4][4];
#pragma unroll
    for (int i = 0; i < 4; ++i)
#pragma unroll
        for (int j = 0; j < 4; ++j) acc[i][j] = 0.0f;

    const float* xb = xin + (size_t)b * CIN * HWPIX;

    for (int c_base = 0; c_base < CIN; c_base += 8) {
        // ---- stage sampled columns: 72 ck x 64 px ----
        for (int s = tid; s < 72 * 64; s += 256) {
            int ckL = s >> 6;
            int px  = s & 63;
            int cp  = ckL / 9;
            int k   = ckL - cp * 9;
            int idx = k * 64 + px;
            int y0 = s_y0[idx], x0 = s_x0[idx];
            float ly = s_ly[idx], lx = s_lx[idx], m = s_m[idx];
            const float* fc = xb + (size_t)(c_base + cp) * HWPIX;
            int basei = y0 * 64 + x0;
            bool yv0 = ((unsigned)y0 < 64u);
            bool yv1 = ((unsigned)(y0 + 1) < 64u);
            bool xv0 = ((unsigned)x0 < 64u);
            bool xv1 = ((unsigned)(x0 + 1) < 64u);
            float v00 = (yv0 & xv0) ? fc[basei]      : 0.0f;
            float v01 = (yv0 & xv1) ? fc[basei + 1]  : 0.0f;
            float v10 = (yv1 & xv0) ? fc[basei + 64] : 0.0f;
            float v11 = (yv1 & xv1) ? fc[basei + 65] : 0.0f;
            float val = ((1.0f - ly) * ((1.0f - lx) * v00 + lx * v01) +
                         ly          * ((1.0f - lx) * v10 + lx * v11)) * m;
            s_col[ckL][px] = val;
        }
        // ---- stage weights: 72 ck x 64 co (wT is [ck][co], coalesced) ----
        {
            int ck_g0 = c_base * 9;   // global ck base for this chunk
            for (int s = tid; s < 72 * 64; s += 256) {
                int ckL = s >> 6;
                int coL = s & 63;
                s_w[ckL][coL] = wT[(size_t)(ck_g0 + ckL) * 256 + co_base + coL];
            }
        }
        __syncthreads();

        // ---- FMA over the 72 ck of this chunk ----
#pragma unroll 4
        for (int ck = 0; ck < 72; ++ck) {
            const float* bp = &s_col[ck][tx * 4];
            const float* ap = &s_w[ck][ty * 4];
            float b0 = bp[0], b1 = bp[1], b2 = bp[2], b3 = bp[3];
            float a0 = ap[0], a1 = ap[1], a2 = ap[2], a3 = ap[3];
            acc[0][0] += a0 * b0; acc[0][1] += a0 * b1; acc[0][2] += a0 * b2; acc[0][3] += a0 * b3;
            acc[1][0] += a1 * b0; acc[1][1] += a1 * b1; acc[1][2] += a1 * b2; acc[1][3] += a1 * b3;
            acc[2][0] += a2 * b0; acc[2][1] += a2 * b1; acc[2][2] += a2 * b2; acc[2][3] += a2 * b3;
            acc[3][0] += a3 * b0; acc[3][1] += a3 * b1; acc[3][2] += a3 * b2; acc[3][3] += a3 * b3;
        }
        __syncthreads();
    }

    // ---- epilogue: add bias, store float4 per co ----
#pragma unroll
    for (int i = 0; i < 4; ++i) {
        int co = co_base + ty * 4 + i;
        float bias = bdcn[co];
        float4 o;
        o.x = acc[i][0] + bias;
        o.y = acc[i][1] + bias;
        o.z = acc[i][2] + bias;
        o.w = acc[i][3] + bias;
        *(float4*)&out[(((size_t)b * COUT + co) << 12) + y * 64 + tx * 4] = o;
    }
}

// ---------------------------------------------------------------------------
extern "C" void kernel_launch(void* const* d_in, const int* in_sizes, int n_in,
                              void* d_out, int out_size, void* d_ws, size_t ws_size,
                              hipStream_t stream)
{
    const float* x    = (const float*)d_in[0];   // [2][256][64][64]
    const float* feat = (const float*)d_in[1];   // [2][256][64][64]
    const float* wom  = (const float*)d_in[2];   // [27][256][3][3]
    const float* bom  = (const float*)d_in[3];   // [27]
    const float* wdcn = (const float*)d_in[4];   // [256][256][3][3]
    const float* bdcn = (const float*)d_in[5];   // [256]
    float* out = (float*)d_out;

    float* om = (float*)d_ws;                    // 2*27*4096   = 221184 floats
    float* wT = om + 2 * 27 * HWPIX;             // 2304*256    = 589824 floats

    conv_om_kernel<<<(2 * 27 * HWPIX) / 256, 256, 0, stream>>>(feat, wom, bom, om);
    transpose_w_kernel<<<(COUT * CKTOT) / 256, 256, 0, stream>>>(wdcn, wT);

    dim3 grid(64, 4, 2);
    dcn_fused_kernel<<<grid, 256, 0, stream>>>(x, om, wT, bdcn, out);
}

// Round 2
// 382.083 us; speedup vs baseline: 1.9803x; 1.9803x over previous
//
#include <hip/hip_runtime.h>
#include <math.h>

#define BATCH 2
#define CIN   256
#define COUT  256
#define COFF  256
#define HWPIX 4096
#define CKTOT 2304
#define VSTR  40          // V row stride in bf16 elems (80 B: 16B-aligned rows)

typedef __attribute__((ext_vector_type(8))) short short8;
typedef __attribute__((ext_vector_type(4))) float float4v;

__device__ __forceinline__ unsigned short f2bf(float f) {
    unsigned u = __float_as_uint(f);
    unsigned r = (u + 0x7FFFu + ((u >> 16) & 1u)) >> 16;   // RNE
    return (unsigned short)r;
}
__device__ __forceinline__ float bf2f(unsigned short h) {
    return __uint_as_float(((unsigned)h) << 16);
}

// ---------------------------------------------------------------------------
// Prep: split w_dcn into bf16 hi/lo in A-fragment-friendly layout
//   whi/wlo[((k*8+cb)*256 + co)*32 + cc]  = split(wdcn[co][cb*32+cc][k])
// so a lane's A-fragment (co=lane&15 row, 8 contiguous c) is one 16B load.
// ---------------------------------------------------------------------------
__global__ __launch_bounds__(256) void wpack_kernel(
    const float* __restrict__ wdcn,            // [256 co][256 c][9 k]
    unsigned short* __restrict__ whi,
    unsigned short* __restrict__ wlo)
{
    int gid = blockIdx.x * 256 + threadIdx.x;  // 0 .. 589823
    int cc  = gid & 31;
    int co  = (gid >> 5) & 255;
    int kcb = gid >> 13;                       // 0..71
    int k   = kcb >> 3;
    int cb  = kcb & 7;
    int c   = cb * 32 + cc;
    float w = wdcn[((size_t)co * 256 + c) * 9 + k];
    unsigned short hi = f2bf(w);
    float lo = w - bf2f(hi);
    whi[gid] = hi;
    wlo[gid] = f2bf(lo);
}

// ---------------------------------------------------------------------------
// conv_om, K-split by 8 channel groups; fp32 atomicAdd into zeroed om.
// ---------------------------------------------------------------------------
__global__ __launch_bounds__(256) void conv_om_kernel(
    const float* __restrict__ feat,   // [2][256][4096]
    const float* __restrict__ wom,    // [27][256][3][3]
    const float* __restrict__ bom,    // [27]
    float* __restrict__ om)           // [2][27][4096] (pre-zeroed)
{
    int gid = blockIdx.x * 256 + threadIdx.x;   // 0 .. 221183
    int g   = blockIdx.y;                       // channel group 0..7
    int p  = gid & 4095;
    int bc = gid >> 12;
    int co = bc % 27;
    int b  = bc / 27;
    int y = p >> 6, x = p & 63;

    float acc = (g == 0) ? bom[co] : 0.0f;
    const float* fb   = feat + (size_t)b * COFF * HWPIX;
    const float* wrow = wom  + (size_t)co * CKTOT;

    for (int c = g * 32; c < g * 32 + 32; ++c) {
        const float* fc = fb + c * HWPIX;
        const float* wc = wrow + c * 9;
#pragma unroll
        for (int ky = 0; ky < 3; ++ky) {
            int yy = y + ky - 1;
            if ((unsigned)yy >= 64u) continue;
#pragma unroll
            for (int kx = 0; kx < 3; ++kx) {
                int xx = x + kx - 1;
                if ((unsigned)xx >= 64u) continue;
                acc += fc[yy * 64 + xx] * wc[ky * 3 + kx];
            }
        }
    }
    atomicAdd(&om[gid], acc);
}

// ---------------------------------------------------------------------------
// Fused deformable sampling + bf16x3 MFMA GEMM.
// Block: batch b, row y, px-half xh -> 256 co x 32 px outputs.
// K-loop: 72 chunks (k 0..8  x  cb 0..7), each = one 16x16x32 MFMA K-step.
// Wave w covers co [w*64, w*64+64) x all 32 px: 4 co-tiles x 2 px-tiles.
// ---------------------------------------------------------------------------
__global__ __launch_bounds__(256) void dcn_mfma_kernel(
    const float* __restrict__ xin,             // [2][256][4096]
    const float* __restrict__ om,              // [2][27][4096]
    const unsigned short* __restrict__ whi,    // packed A hi
    const unsigned short* __restrict__ wlo,    // packed A lo
    const float* __restrict__ bdcn,            // [256]
    float* __restrict__ out)                   // [2][256][4096]
{
    const int tid = threadIdx.x;
    const int y   = blockIdx.x;        // 0..63
    const int xh  = blockIdx.y;        // 0..1
    const int b   = blockIdx.z;        // 0..1

    __shared__ float s_ly[9 * 32], s_lx[9 * 32], s_mk[9 * 32];
    __shared__ int   s_y0[9 * 32], s_x0[9 * 32];
    __shared__ unsigned short Vhi[32 * VSTR];
    __shared__ unsigned short Vlo[32 * VSTR];

    // ---- prologue: sampling coords for this block's 32 px x 9 k ----
    for (int idx = tid; idx < 9 * 32; idx += 256) {
        int k  = idx >> 5;
        int pxl = idx & 31;
        int xg = xh * 32 + pxl;
        int p  = y * 64 + xg;
        const float* omb = om + (size_t)b * 27 * HWPIX;
        float dy = omb[(2 * k) * HWPIX + p];
        float dx = omb[(2 * k + 1) * HWPIX + p];
        float mm = omb[(18 + k) * HWPIX + p];
        float ys = (float)(y  - 1 + (k / 3)) + dy;
        float xs = (float)(xg - 1 + (k % 3)) + dx;
        float y0f = floorf(ys);
        float x0f = floorf(xs);
        s_y0[idx] = (int)y0f;
        s_x0[idx] = (int)x0f;
        s_ly[idx] = ys - y0f;
        s_lx[idx] = xs - x0f;
        s_mk[idx] = 1.0f / (1.0f + expf(-mm));
    }
    __syncthreads();

    const int w    = tid >> 6;        // wave 0..3 -> co base w*64
    const int lane = tid & 63;
    const int l15  = lane & 15;
    const int q    = lane >> 4;       // quad

    // sampling assignment: px = tid&31, 4 channels cc = g*4..g*4+3
    const int spx = tid & 31;
    const int sg  = tid >> 5;         // 0..7

    float4v acc[4][2];
#pragma unroll
    for (int t = 0; t < 4; ++t)
#pragma unroll
        for (int p = 0; p < 2; ++p) acc[t][p] = (float4v)0.0f;

    const float* xb = xin + (size_t)b * CIN * HWPIX;

    for (int kcb = 0; kcb < 72; ++kcb) {
        const int k  = kcb >> 3;
        const int cb = kcb & 7;

        // ---- sample 4 channels for (k, spx), write B-fragments to LDS ----
        {
            int cidx = k * 32 + spx;
            int y0 = s_y0[cidx], x0 = s_x0[cidx];
            float ly = s_ly[cidx], lx = s_lx[cidx], m = s_mk[cidx];
            bool yv0 = ((unsigned)y0 < 64u), yv1 = ((unsigned)(y0 + 1) < 64u);
            bool xv0 = ((unsigned)x0 < 64u), xv1 = ((unsigned)(x0 + 1) < 64u);
            float w00 = (1.0f - ly) * (1.0f - lx) * m;
            float w01 = (1.0f - ly) * lx * m;
            float w10 = ly * (1.0f - lx) * m;
            float w11 = ly * lx * m;
            int basei = y0 * 64 + x0;
            const float* fc = xb + (size_t)(cb * 32 + sg * 4) * HWPIX;
            unsigned hv[2], lv[2];
            unsigned short hs[4], ls[4];
#pragma unroll
            for (int j = 0; j < 4; ++j) {
                float v00 = (yv0 & xv0) ? fc[basei]      : 0.0f;
                float v01 = (yv0 & xv1) ? fc[basei + 1]  : 0.0f;
                float v10 = (yv1 & xv0) ? fc[basei + 64] : 0.0f;
                float v11 = (yv1 & xv1) ? fc[basei + 65] : 0.0f;
                float val = w00 * v00 + w01 * v01 + w10 * v10 + w11 * v11;
                unsigned short hi = f2bf(val);
                hs[j] = hi;
                ls[j] = f2bf(val - bf2f(hi));
                fc += HWPIX;
            }
            hv[0] = (unsigned)hs[0] | ((unsigned)hs[1] << 16);
            hv[1] = (unsigned)hs[2] | ((unsigned)hs[3] << 16);
            lv[0] = (unsigned)ls[0] | ((unsigned)ls[1] << 16);
            lv[1] = (unsigned)ls[2] | ((unsigned)ls[3] << 16);
            *(uint2*)&Vhi[spx * VSTR + sg * 4] = make_uint2(hv[0], hv[1]);
            *(uint2*)&Vlo[spx * VSTR + sg * 4] = make_uint2(lv[0], lv[1]);
        }

        // ---- A fragments direct from global (L2-resident, wave-coalesced) ----
        short8 ah[4], al[4];
#pragma unroll
        for (int t = 0; t < 4; ++t) {
            int co = w * 64 + t * 16 + l15;
            size_t off = ((size_t)kcb * 256 + co) * 32 + q * 8;
            ah[t] = *(const short8*)(whi + off);
            al[t] = *(const short8*)(wlo + off);
        }

        __syncthreads();

        short8 bh[2], bl[2];
#pragma unroll
        for (int p = 0; p < 2; ++p) {
            int px = p * 16 + l15;
            bh[p] = *(const short8*)&Vhi[px * VSTR + q * 8];
            bl[p] = *(const short8*)&Vlo[px * VSTR + q * 8];
        }

#pragma unroll
        for (int t = 0; t < 4; ++t) {
#pragma unroll
            for (int p = 0; p < 2; ++p) {
                acc[t][p] = __builtin_amdgcn_mfma_f32_16x16x32_bf16(ah[t], bh[p], acc[t][p], 0, 0, 0);
                acc[t][p] = __builtin_amdgcn_mfma_f32_16x16x32_bf16(ah[t], bl[p], acc[t][p], 0, 0, 0);
                acc[t][p] = __builtin_amdgcn_mfma_f32_16x16x32_bf16(al[t], bh[p], acc[t][p], 0, 0, 0);
            }
        }

        __syncthreads();
    }

    // ---- epilogue: bias + store. D layout: row(co)=q*4+r, col(px)=l15 ----
#pragma unroll
    for (int t = 0; t < 4; ++t) {
#pragma unroll
        for (int r = 0; r < 4; ++r) {
            int co = w * 64 + t * 16 + q * 4 + r;
            float bias = bdcn[co];
#pragma unroll
            for (int p = 0; p < 2; ++p) {
                int px = xh * 32 + p * 16 + l15;
                out[(((size_t)b * COUT + co) << 12) + y * 64 + px] = acc[t][p][r] + bias;
            }
        }
    }
}

// ---------------------------------------------------------------------------
extern "C" void kernel_launch(void* const* d_in, const int* in_sizes, int n_in,
                              void* d_out, int out_size, void* d_ws, size_t ws_size,
                              hipStream_t stream)
{
    const float* x    = (const float*)d_in[0];
    const float* feat = (const float*)d_in[1];
    const float* wom  = (const float*)d_in[2];
    const float* bom  = (const float*)d_in[3];
    const float* wdcn = (const float*)d_in[4];
    const float* bdcn = (const float*)d_in[5];
    float* out = (float*)d_out;

    // workspace layout
    float* om = (float*)d_ws;                               // 221184 f32
    unsigned short* whi = (unsigned short*)(om + 2 * 27 * HWPIX);
    unsigned short* wlo = whi + (size_t)CKTOT * 256;        // 589824 each

    hipMemsetAsync(om, 0, (size_t)2 * 27 * HWPIX * sizeof(float), stream);

    wpack_kernel<<<(CKTOT * 256) / 256, 256, 0, stream>>>(wdcn, whi, wlo);

    dim3 gco(221184 / 256, 8);
    conv_om_kernel<<<gco, 256, 0, stream>>>(feat, wom, bom, om);

    dim3 grid(64, 2, 2);
    dcn_mfma_kernel<<<grid, 256, 0, stream>>>(x, om, whi, wlo, bdcn, out);
}

// Round 3
// 270.004 us; speedup vs baseline: 2.8023x; 1.4151x over previous
//
#include <hip/hip_runtime.h>
#include <math.h>

#define BATCH 2
#define CIN   256
#define COUT  256
#define COFF  256
#define HWPIX 4096
#define CKTOT 2304
#define VSTR  40          // Vhi/Vlo row stride in bf16 elems (80 B, 16B-aligned)

typedef __attribute__((ext_vector_type(8))) short short8;
typedef __attribute__((ext_vector_type(4))) float float4v;

__device__ __forceinline__ unsigned short f2bf(float f) {
    unsigned u = __float_as_uint(f);
    unsigned r = (u + 0x7FFFu + ((u >> 16) & 1u)) >> 16;   // RNE
    return (unsigned short)r;
}
__device__ __forceinline__ float bf2f(unsigned short h) {
    return __uint_as_float(((unsigned)h) << 16);
}

// ---------------------------------------------------------------------------
// xT[b][p][c] = x[b][c][p]   (NHWC for coalesced bilinear gathers)
// ---------------------------------------------------------------------------
__global__ __launch_bounds__(256) void xpose_kernel(
    const float* __restrict__ x, float* __restrict__ xT)
{
    int b  = blockIdx.z;
    int pt = blockIdx.x;     // 128 tiles of 32 px
    int ct = blockIdx.y;     // 8 tiles of 32 c
    __shared__ float t[32][33];
    int tx = threadIdx.x & 31, ty = threadIdx.x >> 5;   // ty 0..7
    const float* xb = x + ((size_t)b * 256 + ct * 32) * HWPIX + pt * 32;
#pragma unroll
    for (int i = ty; i < 32; i += 8)
        t[i][tx] = xb[(size_t)i * HWPIX + tx];          // coalesced in p
    __syncthreads();
    float* ob = xT + ((size_t)b * HWPIX + pt * 32) * 256 + ct * 32;
#pragma unroll
    for (int i = ty; i < 32; i += 8)
        ob[(size_t)i * 256 + tx] = t[tx][i];            // coalesced in c
}

// ---------------------------------------------------------------------------
// womT[c][co][kk] = wom[co][c][kk]   (block-uniform weight reads -> s_load)
// ---------------------------------------------------------------------------
__global__ __launch_bounds__(256) void womT_kernel(
    const float* __restrict__ wom, float* __restrict__ womT)
{
    int gid = blockIdx.x * 256 + threadIdx.x;   // < 62208
    int c  = gid / 243;
    int r  = gid - c * 243;
    int co = r / 9;
    int kk = r - co * 9;
    womT[gid] = wom[(size_t)co * CKTOT + c * 9 + kk];
}

// ---------------------------------------------------------------------------
// w_dcn split to bf16 hi/lo, A-fragment layout whi[((k*8+cb)*256+co)*32+cc]
// ---------------------------------------------------------------------------
__global__ __launch_bounds__(256) void wpack_kernel(
    const float* __restrict__ wdcn,
    unsigned short* __restrict__ whi,
    unsigned short* __restrict__ wlo)
{
    int gid = blockIdx.x * 256 + threadIdx.x;  // 0 .. 589823
    int cc  = gid & 31;
    int co  = (gid >> 5) & 255;
    int kcb = gid >> 13;                       // 0..71
    int k   = kcb >> 3;
    int cb  = kcb & 7;
    int c   = cb * 32 + cc;
    float w = wdcn[((size_t)co * 256 + c) * 9 + k];
    unsigned short hi = f2bf(w);
    whi[gid] = hi;
    wlo[gid] = f2bf(w - bf2f(hi));
}

// ---------------------------------------------------------------------------
// conv_om v2: LDS-tiled, scalar-broadcast weights.
// grid (8 cgroups, 16 ygroups, 2 b); block 256 = 4 rows x 64 px.
// ---------------------------------------------------------------------------
#define CH_TILE 4
__global__ __launch_bounds__(256) void conv_om2_kernel(
    const float* __restrict__ feat,   // [2][256][4096]
    const float* __restrict__ womT,   // [256][27][9]
    const float* __restrict__ bom,    // [27]
    float* __restrict__ om)           // [2][27][4096] pre-zeroed
{
    const int g  = blockIdx.x;        // channel group 0..7
    const int yg = blockIdx.y;        // 0..15
    const int b  = blockIdx.z;
    const int tid = threadIdx.x;
    const int ry = tid >> 6;          // 0..3
    const int x  = tid & 63;
    const int y  = yg * 4 + ry;

    __shared__ float sF[CH_TILE][6][66];

    float acc[27];
#pragma unroll
    for (int co = 0; co < 27; ++co) acc[co] = 0.0f;

    const float* fb = feat + (size_t)b * COFF * HWPIX;

    for (int c0 = g * 32; c0 < g * 32 + 32; c0 += CH_TILE) {
        __syncthreads();
        // stage CH_TILE channels of rows yg*4-1 .. yg*4+4, cols -1..64
        for (int idx = tid; idx < CH_TILE * 396; idx += 256) {
            int cc  = idx / 396;
            int r   = idx - cc * 396;
            int row = r / 66;
            int col = r - row * 66 - 1;
            int gy  = yg * 4 - 1 + row;
            float v = 0.0f;
            if ((unsigned)gy < 64u && (unsigned)col < 64u)
                v = fb[(size_t)(c0 + cc) * HWPIX + gy * 64 + col];
            sF[cc][row][col + 1] = v;
        }
        __syncthreads();

#pragma unroll
        for (int cc = 0; cc < CH_TILE; ++cc) {
            float v[9];
#pragma unroll
            for (int dy = 0; dy < 3; ++dy)
#pragma unroll
                for (int dx = 0; dx < 3; ++dx)
                    v[dy * 3 + dx] = sF[cc][ry + dy][x + dx];
            const float* wr = womT + (size_t)(c0 + cc) * 243;  // uniform
#pragma unroll
            for (int co = 0; co < 27; ++co) {
#pragma unroll
                for (int kk = 0; kk < 9; ++kk)
                    acc[co] += v[kk] * wr[co * 9 + kk];
            }
        }
    }

    const int p = y * 64 + x;
    float* ob = om + (size_t)b * 27 * HWPIX;
#pragma unroll
    for (int co = 0; co < 27; ++co) {
        float a = acc[co] + (g == 0 ? bom[co] : 0.0f);
        atomicAdd(&ob[co * HWPIX + p], a);
    }
}

// ---------------------------------------------------------------------------
// Fused deformable sampling + bf16x3 MFMA GEMM, NHWC gathers.
// Block: (y, xq, b) -> 256 co x 16 px. Grid 64x4x2 = 512 blocks.
// Chunk kcb = k*8+cb : one 16x16x32 K-step over channels cb*32..+31, tap k.
// ---------------------------------------------------------------------------
__global__ __launch_bounds__(256) void dcn_mfma_kernel(
    const float* __restrict__ xT,              // [2][4096][256]
    const float* __restrict__ om,              // [2][27][4096]
    const unsigned short* __restrict__ whi,
    const unsigned short* __restrict__ wlo,
    const float* __restrict__ bdcn,
    float* __restrict__ out)                   // [2][256][4096]
{
    const int tid = threadIdx.x;
    const int y   = blockIdx.x;        // 0..63
    const int xq  = blockIdx.y;        // 0..3 (16-px quarters)
    const int b   = blockIdx.z;

    __shared__ float s_w00[144], s_w01[144], s_w10[144], s_w11[144];
    __shared__ int   s_i00[144], s_i01[144], s_i10[144], s_i11[144];
    __shared__ unsigned short Vhi[16 * VSTR];
    __shared__ unsigned short Vlo[16 * VSTR];

    // ---- prologue: per (k, px) bilinear weights + clamped corner indices ----
    if (tid < 144) {
        int k   = tid >> 4;            // 0..8
        int pxl = tid & 15;
        int xg  = xq * 16 + pxl;
        int p   = y * 64 + xg;
        const float* omb = om + (size_t)b * 27 * HWPIX;
        float dy = omb[(2 * k) * HWPIX + p];
        float dx = omb[(2 * k + 1) * HWPIX + p];
        float mm = omb[(18 + k) * HWPIX + p];
        float ys = (float)(y  - 1 + (k / 3)) + dy;
        float xs = (float)(xg - 1 + (k % 3)) + dx;
        float y0f = floorf(ys), x0f = floorf(xs);
        int y0 = (int)y0f, x0 = (int)x0f;
        float ly = ys - y0f, lx = xs - x0f;
        float m  = 1.0f / (1.0f + expf(-mm));
        bool yv0 = ((unsigned)y0 < 64u), yv1 = ((unsigned)(y0 + 1) < 64u);
        bool xv0 = ((unsigned)x0 < 64u), xv1 = ((unsigned)(x0 + 1) < 64u);
        float w00 = (1.0f - ly) * (1.0f - lx) * m;
        float w01 = (1.0f - ly) * lx * m;
        float w10 = ly * (1.0f - lx) * m;
        float w11 = ly * lx * m;
        int i00 = y0 * 64 + x0;
        s_w00[tid] = (yv0 && xv0) ? w00 : 0.0f;  s_i00[tid] = (yv0 && xv0) ? i00      : 0;
        s_w01[tid] = (yv0 && xv1) ? w01 : 0.0f;  s_i01[tid] = (yv0 && xv1) ? i00 + 1  : 0;
        s_w10[tid] = (yv1 && xv0) ? w10 : 0.0f;  s_i10[tid] = (yv1 && xv0) ? i00 + 64 : 0;
        s_w11[tid] = (yv1 && xv1) ? w11 : 0.0f;  s_i11[tid] = (yv1 && xv1) ? i00 + 65 : 0;
    }
    __syncthreads();

    const int w    = tid >> 6;        // wave -> co base w*64
    const int lane = tid & 63;
    const int l15  = lane & 15;
    const int q    = lane >> 4;

    // sampling assignment: 16 consecutive lanes = same px, channel pairs 0..15
    const int cpair = tid & 15;       // channels cb*32 + cpair*2 (+1)
    const int spx   = (tid >> 4) & 15;

    float4v acc[4];
#pragma unroll
    for (int t = 0; t < 4; ++t) acc[t] = (float4v)0.0f;

    const float* xb = xT + ((size_t)b << 12) * 256;

    for (int kcb = 0; kcb < 72; ++kcb) {
        const int k  = kcb >> 3;
        const int cb = kcb & 7;

        // ---- sample 2 channels at (k, spx): 4 coalesced float2 gathers ----
        {
            int cidx = k * 16 + spx;
            float w00 = s_w00[cidx], w01 = s_w01[cidx];
            float w10 = s_w10[cidx], w11 = s_w11[cidx];
            int i00 = s_i00[cidx], i01 = s_i01[cidx];
            int i10 = s_i10[cidx], i11 = s_i11[cidx];
            const float* xc = xb + cb * 32 + cpair * 2;
            float2 v00 = *(const float2*)(xc + (size_t)i00 * 256);
            float2 v01 = *(const float2*)(xc + (size_t)i01 * 256);
            float2 v10 = *(const float2*)(xc + (size_t)i10 * 256);
            float2 v11 = *(const float2*)(xc + (size_t)i11 * 256);
            float va = w00 * v00.x + w01 * v01.x + w10 * v10.x + w11 * v11.x;
            float vb = w00 * v00.y + w01 * v01.y + w10 * v10.y + w11 * v11.y;
            unsigned short ha = f2bf(va), hb = f2bf(vb);
            unsigned short la = f2bf(va - bf2f(ha)), lb = f2bf(vb - bf2f(hb));
            *(unsigned*)&Vhi[spx * VSTR + cpair * 2] = (unsigned)ha | ((unsigned)hb << 16);
            *(unsigned*)&Vlo[spx * VSTR + cpair * 2] = (unsigned)la | ((unsigned)lb << 16);
        }

        // ---- A fragments from global (L2-resident, coalesced) ----
        short8 ah[4], al[4];
#pragma unroll
        for (int t = 0; t < 4; ++t) {
            int co = w * 64 + t * 16 + l15;
            size_t off = ((size_t)kcb * 256 + co) * 32 + q * 8;
            ah[t] = *(const short8*)(whi + off);
            al[t] = *(const short8*)(wlo + off);
        }

        __syncthreads();

        short8 bh = *(const short8*)&Vhi[l15 * VSTR + q * 8];
        short8 bl = *(const short8*)&Vlo[l15 * VSTR + q * 8];

#pragma unroll
        for (int t = 0; t < 4; ++t) {
            acc[t] = __builtin_amdgcn_mfma_f32_16x16x32_bf16(ah[t], bh, acc[t], 0, 0, 0);
            acc[t] = __builtin_amdgcn_mfma_f32_16x16x32_bf16(ah[t], bl, acc[t], 0, 0, 0);
            acc[t] = __builtin_amdgcn_mfma_f32_16x16x32_bf16(al[t], bh, acc[t], 0, 0, 0);
        }

        __syncthreads();
    }

    // ---- epilogue: bias + store (D: row co = q*4+r, col px = l15) ----
#pragma unroll
    for (int t = 0; t < 4; ++t) {
#pragma unroll
        for (int r = 0; r < 4; ++r) {
            int co = w * 64 + t * 16 + q * 4 + r;
            out[(((size_t)b * COUT + co) << 12) + y * 64 + xq * 16 + l15]
                = acc[t][r] + bdcn[co];
        }
    }
}

// ---------------------------------------------------------------------------
extern "C" void kernel_launch(void* const* d_in, const int* in_sizes, int n_in,
                              void* d_out, int out_size, void* d_ws, size_t ws_size,
                              hipStream_t stream)
{
    const float* x    = (const float*)d_in[0];
    const float* feat = (const float*)d_in[1];
    const float* wom  = (const float*)d_in[2];
    const float* bom  = (const float*)d_in[3];
    const float* wdcn = (const float*)d_in[4];
    const float* bdcn = (const float*)d_in[5];
    float* out = (float*)d_out;

    // workspace layout
    float* om            = (float*)d_ws;                    // 221184 f32
    unsigned short* whi  = (unsigned short*)(om + 2 * 27 * HWPIX);
    unsigned short* wlo  = whi + (size_t)CKTOT * 256;       // 589824 each
    float* womT          = (float*)(wlo + (size_t)CKTOT * 256);  // 62208 f32
    float* xT            = womT + 62208;                    // 2*4096*256 f32

    hipMemsetAsync(om, 0, (size_t)2 * 27 * HWPIX * sizeof(float), stream);

    dim3 gxp(128, 8, 2);
    xpose_kernel<<<gxp, 256, 0, stream>>>(x, xT);
    womT_kernel<<<243, 256, 0, stream>>>(wom, womT);
    wpack_kernel<<<(CKTOT * 256) / 256, 256, 0, stream>>>(wdcn, whi, wlo);

    dim3 gco(8, 16, 2);
    conv_om2_kernel<<<gco, 256, 0, stream>>>(feat, womT, bom, om);

    dim3 grid(64, 4, 2);
    dcn_mfma_kernel<<<grid, 256, 0, stream>>>(xT, om, whi, wlo, bdcn, out);
}

// Round 4
// 169.878 us; speedup vs baseline: 4.4540x; 1.5894x over previous
//
#include <hip/hip_runtime.h>
#include <math.h>

#define BATCH 2
#define CIN   256
#define COUT  256
#define COFF  256
#define HWPIX 4096
#define CKTOT 2304

typedef __attribute__((ext_vector_type(8))) short short8;
typedef __attribute__((ext_vector_type(4))) float float4v;

__device__ __forceinline__ unsigned short f2bf(float f) {
    unsigned u = __float_as_uint(f);
    unsigned r = (u + 0x7FFFu + ((u >> 16) & 1u)) >> 16;   // RNE
    return (unsigned short)r;
}
__device__ __forceinline__ unsigned short f2bf_trunc(float f) {
    return (unsigned short)(__float_as_uint(f) >> 16);
}
__device__ __forceinline__ float bf2f(unsigned short h) {
    return __uint_as_float(((unsigned)h) << 16);
}

// ---------------------------------------------------------------------------
// NHWC transposes: z 0..1 -> x->xT, z 2..3 -> feat->featT
// ---------------------------------------------------------------------------
__global__ __launch_bounds__(256) void xpose_both_kernel(
    const float* __restrict__ x, const float* __restrict__ feat,
    float* __restrict__ xT, float* __restrict__ featT)
{
    int z  = blockIdx.z;
    int b  = z & 1;
    const float* src = (z < 2) ? x : feat;
    float* dst       = (z < 2) ? xT : featT;
    int pt = blockIdx.x;     // 128 tiles of 32 px
    int ct = blockIdx.y;     // 8 tiles of 32 c
    __shared__ float t[32][33];
    int tx = threadIdx.x & 31, ty = threadIdx.x >> 5;
    const float* sb = src + ((size_t)b * 256 + ct * 32) * HWPIX + pt * 32;
#pragma unroll
    for (int i = ty; i < 32; i += 8)
        t[i][tx] = sb[(size_t)i * HWPIX + tx];
    __syncthreads();
    float* ob = dst + ((size_t)b * HWPIX + pt * 32) * 256 + ct * 32;
#pragma unroll
    for (int i = ty; i < 32; i += 8)
        ob[(size_t)i * 256 + tx] = t[tx][i];
}

// ---------------------------------------------------------------------------
// w_dcn split to bf16 hi/lo: whi[((kcb)*256+co)*32+cc], kcb=k*8+cb, c=cb*32+cc
// ---------------------------------------------------------------------------
__global__ __launch_bounds__(256) void wpack_kernel(
    const float* __restrict__ wdcn,
    unsigned short* __restrict__ whi,
    unsigned short* __restrict__ wlo)
{
    int gid = blockIdx.x * 256 + threadIdx.x;  // 0 .. 589823
    int cc  = gid & 31;
    int co  = (gid >> 5) & 255;
    int kcb = gid >> 13;                       // 0..71
    int k   = kcb >> 3;
    int cb  = kcb & 7;
    int c   = cb * 32 + cc;
    float w = wdcn[((size_t)co * 256 + c) * 9 + k];
    unsigned short hi = f2bf(w);
    whi[gid] = hi;
    wlo[gid] = f2bf_trunc(w - bf2f(hi));
}

// ---------------------------------------------------------------------------
// w_offset_mask packed for MFMA: wohi[(kcb*32+co)*32+cc], co 27..31 zero-pad
// ---------------------------------------------------------------------------
__global__ __launch_bounds__(256) void wpack_om_kernel(
    const float* __restrict__ wom,             // [27][256][9]
    unsigned short* __restrict__ wohi,
    unsigned short* __restrict__ wolo)
{
    int gid = blockIdx.x * 256 + threadIdx.x;  // 0 .. 73727
    int cc  = gid & 31;
    int co  = (gid >> 5) & 31;
    int kcb = gid >> 10;                       // 0..71
    int k   = kcb >> 3;
    int cb  = kcb & 7;
    float w = 0.0f;
    if (co < 27) w = wom[(size_t)co * CKTOT + (cb * 32 + cc) * 9 + k];
    unsigned short hi = f2bf(w);
    wohi[gid] = hi;
    wolo[gid] = f2bf_trunc(w - bf2f(hi));
}

// ---------------------------------------------------------------------------
// conv_om via MFMA bf16x3. Block = 4 waves x 16 px = one row y; M=32 (27).
// K-split: kg 0..3 -> 18 chunks each; fp32 atomicAdd into zeroed om.
// No LDS, no barriers: B-fragments read directly from featT (NHWC).
// ---------------------------------------------------------------------------
__global__ __launch_bounds__(256) void conv_om_mfma_kernel(
    const float* __restrict__ featT,           // [2][4096][256]
    const unsigned short* __restrict__ wohi,
    const unsigned short* __restrict__ wolo,
    const float* __restrict__ bom,             // [27]
    float* __restrict__ om)                    // [2][27][4096] pre-zeroed
{
    const int y  = blockIdx.x;     // 0..63
    const int kg = blockIdx.y;     // 0..3
    const int b  = blockIdx.z;
    const int tid = threadIdx.x;
    const int wv  = tid >> 6;
    const int lane = tid & 63;
    const int l15 = lane & 15;
    const int q   = lane >> 4;
    const int xg  = wv * 16 + l15;             // column within row y

    float4v acc[2];
    acc[0] = (float4v)0.0f;
    acc[1] = (float4v)0.0f;

    const float* fb = featT + ((size_t)b << 12) * 256;

    for (int i = 0; i < 18; ++i) {
        int kcb = kg * 18 + i;
        int k  = kcb >> 3;
        int cb = kcb & 7;
        int dy = k / 3 - 1, dx = k % 3 - 1;
        int yy = y + dy, xx = xg + dx;
        bool valid = ((unsigned)yy < 64u) & ((unsigned)xx < 64u);
        float4 f0 = make_float4(0.f, 0.f, 0.f, 0.f);
        float4 f1 = make_float4(0.f, 0.f, 0.f, 0.f);
        if (valid) {
            const float* src = fb + ((size_t)(yy * 64 + xx)) * 256 + cb * 32 + q * 8;
            f0 = *(const float4*)src;
            f1 = *(const float4*)(src + 4);
        }
        float v[8] = {f0.x, f0.y, f0.z, f0.w, f1.x, f1.y, f1.z, f1.w};
        union { short8 s; unsigned u[4]; } bh, bl;
#pragma unroll
        for (int j = 0; j < 4; ++j) {
            unsigned short h0 = f2bf(v[2 * j]);
            unsigned short h1 = f2bf(v[2 * j + 1]);
            unsigned short l0 = f2bf_trunc(v[2 * j]     - bf2f(h0));
            unsigned short l1 = f2bf_trunc(v[2 * j + 1] - bf2f(h1));
            bh.u[j] = (unsigned)h0 | ((unsigned)h1 << 16);
            bl.u[j] = (unsigned)l0 | ((unsigned)l1 << 16);
        }
        short8 ah[2], al[2];
#pragma unroll
        for (int t = 0; t < 2; ++t) {
            size_t off = ((size_t)kcb * 32 + t * 16 + l15) * 32 + q * 8;
            ah[t] = *(const short8*)(wohi + off);
            al[t] = *(const short8*)(wolo + off);
        }
#pragma unroll
        for (int t = 0; t < 2; ++t) {
            acc[t] = __builtin_amdgcn_mfma_f32_16x16x32_bf16(ah[t], bh.s, acc[t], 0, 0, 0);
            acc[t] = __builtin_amdgcn_mfma_f32_16x16x32_bf16(ah[t], bl.s, acc[t], 0, 0, 0);
            acc[t] = __builtin_amdgcn_mfma_f32_16x16x32_bf16(al[t], bh.s, acc[t], 0, 0, 0);
        }
    }

    const int p = y * 64 + xg;
    float* ob = om + (size_t)b * 27 * HWPIX;
#pragma unroll
    for (int t = 0; t < 2; ++t) {
#pragma unroll
        for (int r = 0; r < 4; ++r) {
            int co = t * 16 + q * 4 + r;
            if (co < 27) {
                float a = acc[t][r] + (kg == 0 ? bom[co] : 0.0f);
                atomicAdd(&ob[co * HWPIX + p], a);
            }
        }
    }
}

// ---------------------------------------------------------------------------
// dcn: fused sampling + bf16x3 MFMA. Block = 256 co x 32 px, kg splits the
// channel range (cb 0..3 / 4..7). cb-batched staging: one barrier pair per
// 32-channel group (9 taps sampled together), then 9 barrier-free MFMA chunks.
// ---------------------------------------------------------------------------
__global__ __launch_bounds__(256) void dcn_mfma_kernel(
    const float* __restrict__ xT,              // [2][4096][256]
    const float* __restrict__ om,              // [2][27][4096]
    const unsigned short* __restrict__ whi,
    const unsigned short* __restrict__ wlo,
    const float* __restrict__ bdcn,
    float* __restrict__ out)                   // [2][256][4096] pre-zeroed
{
    const int tid = threadIdx.x;
    const int y   = blockIdx.x >> 1;           // 0..63
    const int xh  = blockIdx.x & 1;            // 0..1 (32-px halves)
    const int kg  = blockIdx.y;                // 0..1 (channel halves)
    const int b   = blockIdx.z;

    __shared__ float s_w00[288], s_w01[288], s_w10[288], s_w11[288];
    __shared__ int   s_i00[288], s_i01[288], s_i10[288], s_i11[288];
    __shared__ unsigned short Vhi[9 * 32 * 32];   // [k][px32][ch32]
    __shared__ unsigned short Vlo[9 * 32 * 32];

    // ---- prologue: bilinear weights + clamped corner indices, 9k x 32px ----
    for (int idx = tid; idx < 288; idx += 256) {
        int k   = idx >> 5;
        int pxl = idx & 31;
        int xg  = xh * 32 + pxl;
        int p   = y * 64 + xg;
        const float* omb = om + (size_t)b * 27 * HWPIX;
        float dy = omb[(2 * k) * HWPIX + p];
        float dx = omb[(2 * k + 1) * HWPIX + p];
        float mm = omb[(18 + k) * HWPIX + p];
        float ys = (float)(y  - 1 + (k / 3)) + dy;
        float xs = (float)(xg - 1 + (k % 3)) + dx;
        float y0f = floorf(ys), x0f = floorf(xs);
        int y0 = (int)y0f, x0 = (int)x0f;
        float ly = ys - y0f, lx = xs - x0f;
        float m  = 1.0f / (1.0f + expf(-mm));
        bool yv0 = ((unsigned)y0 < 64u), yv1 = ((unsigned)(y0 + 1) < 64u);
        bool xv0 = ((unsigned)x0 < 64u), xv1 = ((unsigned)(x0 + 1) < 64u);
        float w00 = (1.0f - ly) * (1.0f - lx) * m;
        float w01 = (1.0f - ly) * lx * m;
        float w10 = ly * (1.0f - lx) * m;
        float w11 = ly * lx * m;
        int i00 = y0 * 64 + x0;
        s_w00[idx] = (yv0 && xv0) ? w00 : 0.0f;  s_i00[idx] = (yv0 && xv0) ? i00      : 0;
        s_w01[idx] = (yv0 && xv1) ? w01 : 0.0f;  s_i01[idx] = (yv0 && xv1) ? i00 + 1  : 0;
        s_w10[idx] = (yv1 && xv0) ? w10 : 0.0f;  s_i10[idx] = (yv1 && xv0) ? i00 + 64 : 0;
        s_w11[idx] = (yv1 && xv1) ? w11 : 0.0f;  s_i11[idx] = (yv1 && xv1) ? i00 + 65 : 0;
    }
    __syncthreads();

    const int w    = tid >> 6;        // wave -> co base w*64
    const int lane = tid & 63;
    const int l15  = lane & 15;
    const int q    = lane >> 4;

    // staging assignment: cg = tid&7 (4 ch), spx = tid>>3 (0..31)
    const int cg  = tid & 7;
    const int spx = tid >> 3;

    float4v acc[4][2];
#pragma unroll
    for (int t = 0; t < 4; ++t)
#pragma unroll
        for (int p = 0; p < 2; ++p) acc[t][p] = (float4v)0.0f;

    const float* xb = xT + ((size_t)b << 12) * 256;

    for (int cbl = 0; cbl < 4; ++cbl) {
        const int cb = kg * 4 + cbl;

        // ---- stage: 9 taps x 32 px x 32 ch, 36 gathers/thread in flight ----
        {
            const float* xc = xb + cb * 32 + cg * 4;
#pragma unroll 3
            for (int k = 0; k < 9; ++k) {
                int cidx = k * 32 + spx;
                float w00 = s_w00[cidx], w01 = s_w01[cidx];
                float w10 = s_w10[cidx], w11 = s_w11[cidx];
                int i00 = s_i00[cidx], i01 = s_i01[cidx];
                int i10 = s_i10[cidx], i11 = s_i11[cidx];
                float4 v00 = *(const float4*)(xc + (size_t)i00 * 256);
                float4 v01 = *(const float4*)(xc + (size_t)i01 * 256);
                float4 v10 = *(const float4*)(xc + (size_t)i10 * 256);
                float4 v11 = *(const float4*)(xc + (size_t)i11 * 256);
                float val[4];
                val[0] = w00 * v00.x + w01 * v01.x + w10 * v10.x + w11 * v11.x;
                val[1] = w00 * v00.y + w01 * v01.y + w10 * v10.y + w11 * v11.y;
                val[2] = w00 * v00.z + w01 * v01.z + w10 * v10.z + w11 * v11.z;
                val[3] = w00 * v00.w + w01 * v01.w + w10 * v10.w + w11 * v11.w;
                unsigned short h[4], l[4];
#pragma unroll
                for (int j = 0; j < 4; ++j) {
                    h[j] = f2bf(val[j]);
                    l[j] = f2bf_trunc(val[j] - bf2f(h[j]));
                }
                uint2 hv = make_uint2((unsigned)h[0] | ((unsigned)h[1] << 16),
                                      (unsigned)h[2] | ((unsigned)h[3] << 16));
                uint2 lv = make_uint2((unsigned)l[0] | ((unsigned)l[1] << 16),
                                      (unsigned)l[2] | ((unsigned)l[3] << 16));
                int vofs = (k * 32 + spx) * 32 + cg * 4;
                *(uint2*)&Vhi[vofs] = hv;
                *(uint2*)&Vlo[vofs] = lv;
            }
        }
        __syncthreads();

        // ---- 9 barrier-free MFMA chunks ----
        for (int k = 0; k < 9; ++k) {
            const int kcb = k * 8 + cb;
            short8 ah[4], al[4];
#pragma unroll
            for (int t = 0; t < 4; ++t) {
                size_t off = ((size_t)kcb * 256 + w * 64 + t * 16 + l15) * 32 + q * 8;
                ah[t] = *(const short8*)(whi + off);
                al[t] = *(const short8*)(wlo + off);
            }
            short8 bh[2], bl[2];
#pragma unroll
            for (int p = 0; p < 2; ++p) {
                int vofs = (k * 32 + p * 16 + l15) * 32 + q * 8;
                bh[p] = *(const short8*)&Vhi[vofs];
                bl[p] = *(const short8*)&Vlo[vofs];
            }
#pragma unroll
            for (int t = 0; t < 4; ++t) {
#pragma unroll
                for (int p = 0; p < 2; ++p) {
                    acc[t][p] = __builtin_amdgcn_mfma_f32_16x16x32_bf16(ah[t], bh[p], acc[t][p], 0, 0, 0);
                    acc[t][p] = __builtin_amdgcn_mfma_f32_16x16x32_bf16(ah[t], bl[p], acc[t][p], 0, 0, 0);
                    acc[t][p] = __builtin_amdgcn_mfma_f32_16x16x32_bf16(al[t], bh[p], acc[t][p], 0, 0, 0);
                }
            }
        }
        __syncthreads();
    }

    // ---- epilogue: atomic accumulate (kg partials); kg0 adds bias ----
#pragma unroll
    for (int t = 0; t < 4; ++t) {
#pragma unroll
        for (int r = 0; r < 4; ++r) {
            int co = w * 64 + t * 16 + q * 4 + r;
            float bias = (kg == 0) ? bdcn[co] : 0.0f;
#pragma unroll
            for (int p = 0; p < 2; ++p) {
                int px = xh * 32 + p * 16 + l15;
                atomicAdd(&out[(((size_t)b * COUT + co) << 12) + y * 64 + px],
                          acc[t][p][r] + bias);
            }
        }
    }
}

// ---------------------------------------------------------------------------
extern "C" void kernel_launch(void* const* d_in, const int* in_sizes, int n_in,
                              void* d_out, int out_size, void* d_ws, size_t ws_size,
                              hipStream_t stream)
{
    const float* x    = (const float*)d_in[0];
    const float* feat = (const float*)d_in[1];
    const float* wom  = (const float*)d_in[2];
    const float* bom  = (const float*)d_in[3];
    const float* wdcn = (const float*)d_in[4];
    const float* bdcn = (const float*)d_in[5];
    float* out = (float*)d_out;

    // workspace layout
    float* om            = (float*)d_ws;                         // 221184 f32
    unsigned short* whi  = (unsigned short*)(om + 2 * 27 * HWPIX);
    unsigned short* wlo  = whi + (size_t)CKTOT * 256;            // 589824 ea
    unsigned short* wohi = wlo + (size_t)CKTOT * 256;            // 73728 ea
    unsigned short* wolo = wohi + 73728;
    float* xT            = (float*)(wolo + 73728);               // 2*4096*256
    float* featT         = xT + (size_t)2 * HWPIX * 256;         // 2*4096*256

    hipMemsetAsync(om, 0, (size_t)2 * 27 * HWPIX * sizeof(float), stream);
    hipMemsetAsync(out, 0, (size_t)2 * COUT * HWPIX * sizeof(float), stream);

    dim3 gxp(128, 8, 4);
    xpose_both_kernel<<<gxp, 256, 0, stream>>>(x, feat, xT, featT);
    wpack_kernel<<<(CKTOT * 256) / 256, 256, 0, stream>>>(wdcn, whi, wlo);
    wpack_om_kernel<<<288, 256, 0, stream>>>(wom, wohi, wolo);

    dim3 gco(64, 4, 2);
    conv_om_mfma_kernel<<<gco, 256, 0, stream>>>(featT, wohi, wolo, bom, om);

    dim3 grid(128, 2, 2);
    dcn_mfma_kernel<<<grid, 256, 0, stream>>>(xT, om, whi, wlo, bdcn, out);
}

// Round 5
// 159.124 us; speedup vs baseline: 4.7550x; 1.0676x over previous
//
#include <hip/hip_runtime.h>
#include <math.h>

#define BATCH 2
#define CIN   256
#define COUT  256
#define COFF  256
#define HWPIX 4096
#define CKTOT 2304
#define VSTR  40            // V row stride in shorts (80 B; 20 words mod 32 -> 2-way, free)
#define PH    66            // padded feat spatial dim
#define PHW   4356          // 66*66

typedef __attribute__((ext_vector_type(8))) short short8;
typedef __attribute__((ext_vector_type(4))) float float4v;

__device__ __forceinline__ unsigned short f2bf(float f) {
    unsigned u = __float_as_uint(f);
    unsigned r = (u + 0x7FFFu + ((u >> 16) & 1u)) >> 16;   // RNE
    return (unsigned short)r;
}
__device__ __forceinline__ unsigned short f2bf_trunc(float f) {
    return (unsigned short)(__float_as_uint(f) >> 16);
}
__device__ __forceinline__ float bf2f(unsigned short h) {
    return __uint_as_float(((unsigned)h) << 16);
}

// ---------------------------------------------------------------------------
// prep: ONE kernel, blockIdx regions:
//   [0,2048)      x -> xT (NHWC)
//   [2048,4096)   feat -> featTp (NHWC, zero-padded 66x66)
//   [4096,6400)   wpack   (w_dcn -> whi/wlo, A-frag layout)
//   [6400,6688)   wpack_om(w_offset_mask -> wohi/wolo, M=32 padded)
//   [6688,6948)   zero featTp borders
//   [6948,8996)   zero out (float4)
// ---------------------------------------------------------------------------
__global__ __launch_bounds__(256) void prep_kernel(
    const float* __restrict__ x, const float* __restrict__ feat,
    const float* __restrict__ wdcn, const float* __restrict__ wom,
    float* __restrict__ xT, float* __restrict__ featTp,
    unsigned short* __restrict__ whi, unsigned short* __restrict__ wlo,
    unsigned short* __restrict__ wohi, unsigned short* __restrict__ wolo,
    float* __restrict__ out)
{
    const int bid = blockIdx.x;
    const int tid = threadIdx.x;

    if (bid < 4096) {
        const bool isx = bid < 2048;
        const int lb = isx ? bid : bid - 2048;
        const int b  = lb >> 10;
        const int r  = lb & 1023;
        const int pt = r >> 3;       // 128 px tiles of 32
        const int ct = r & 7;        // 8 ch tiles of 32
        __shared__ float t[32][33];
        const int tx = tid & 31, ty = tid >> 5;
        const float* src = isx ? x : feat;
        const float* sb = src + ((size_t)b * 256 + ct * 32) * HWPIX + pt * 32;
#pragma unroll
        for (int i = ty; i < 32; i += 8)
            t[i][tx] = sb[(size_t)i * HWPIX + tx];
        __syncthreads();
        if (isx) {
            float* ob = xT + ((size_t)b * HWPIX + pt * 32) * 256 + ct * 32;
#pragma unroll
            for (int i = ty; i < 32; i += 8)
                ob[(size_t)i * 256 + tx] = t[tx][i];
        } else {
#pragma unroll
            for (int i = ty; i < 32; i += 8) {
                int p = pt * 32 + i;
                int row = (p >> 6) + 1, col = (p & 63) + 1;
                featTp[((size_t)b * PHW + row * PH + col) * 256 + ct * 32 + tx] = t[tx][i];
            }
        }
    } else if (bid < 6400) {
        int gid = (bid - 4096) * 256 + tid;    // 0..589823
        int cc  = gid & 31;
        int co  = (gid >> 5) & 255;
        int kcb = gid >> 13;
        int k   = kcb >> 3;
        int cb  = kcb & 7;
        float w = wdcn[((size_t)co * 256 + cb * 32 + cc) * 9 + k];
        unsigned short hi = f2bf(w);
        whi[gid] = hi;
        wlo[gid] = f2bf_trunc(w - bf2f(hi));
    } else if (bid < 6688) {
        int gid = (bid - 6400) * 256 + tid;    // 0..73727
        int cc  = gid & 31;
        int co  = (gid >> 5) & 31;
        int kcb = gid >> 10;
        int k   = kcb >> 3;
        int cb  = kcb & 7;
        float w = 0.0f;
        if (co < 27) w = wom[(size_t)co * CKTOT + (cb * 32 + cc) * 9 + k];
        unsigned short hi = f2bf(w);
        wohi[gid] = hi;
        wolo[gid] = f2bf_trunc(w - bf2f(hi));
    } else if (bid < 6948) {
        int idx = (bid - 6688) * 256 + tid;    // < 133120
        if (idx < 133120) {
            int b = idx / 66560;
            int r = idx - b * 66560;
            int pidx = r >> 8;                 // 0..259 border cells
            int c = r & 255;
            int row, col;
            if (pidx < 66)       { row = 0;           col = pidx; }
            else if (pidx < 132) { row = 65;          col = pidx - 66; }
            else if (pidx < 196) { row = pidx - 131;  col = 0; }
            else                 { row = pidx - 195;  col = 65; }
            featTp[((size_t)b * PHW + row * PH + col) * 256 + c] = 0.0f;
        }
    } else {
        int idx = (bid - 6948) * 256 + tid;    // < 524288 float4
        ((float4*)out)[idx] = make_float4(0.f, 0.f, 0.f, 0.f);
    }
}

// ---------------------------------------------------------------------------
// conv_om via MFMA bf16x3, branchless (padded featTp), no atomics:
// each kg writes its own partial plane om4[kg][b][27][4096].
// ---------------------------------------------------------------------------
__global__ __launch_bounds__(256) void conv_om_mfma_kernel(
    const float* __restrict__ featTp,          // [2][4356][256]
    const unsigned short* __restrict__ wohi,
    const unsigned short* __restrict__ wolo,
    float* __restrict__ om4)                   // [4][2][27][4096]
{
    const int y  = blockIdx.x;     // 0..63
    const int kg = blockIdx.y;     // 0..3
    const int b  = blockIdx.z;
    const int tid = threadIdx.x;
    const int wv  = tid >> 6;
    const int lane = tid & 63;
    const int l15 = lane & 15;
    const int q   = lane >> 4;
    const int xg  = wv * 16 + l15;

    float4v acc[2];
    acc[0] = (float4v)0.0f;
    acc[1] = (float4v)0.0f;

    const float* fb = featTp + (size_t)b * PHW * 256;

    for (int i = 0; i < 18; ++i) {
        int kcb = kg * 18 + i;
        int k  = kcb >> 3;
        int cb = kcb & 7;
        const float* src = fb + ((size_t)((y + k / 3) * PH + xg + k % 3)) * 256
                              + cb * 32 + q * 8;
        float4 f0 = *(const float4*)src;
        float4 f1 = *(const float4*)(src + 4);
        float v[8] = {f0.x, f0.y, f0.z, f0.w, f1.x, f1.y, f1.z, f1.w};
        union { short8 s; unsigned u[4]; } bh, bl;
#pragma unroll
        for (int j = 0; j < 4; ++j) {
            unsigned short h0 = f2bf(v[2 * j]);
            unsigned short h1 = f2bf(v[2 * j + 1]);
            unsigned short l0 = f2bf_trunc(v[2 * j]     - bf2f(h0));
            unsigned short l1 = f2bf_trunc(v[2 * j + 1] - bf2f(h1));
            bh.u[j] = (unsigned)h0 | ((unsigned)h1 << 16);
            bl.u[j] = (unsigned)l0 | ((unsigned)l1 << 16);
        }
        short8 ah[2], al[2];
#pragma unroll
        for (int t = 0; t < 2; ++t) {
            size_t off = ((size_t)kcb * 32 + t * 16 + l15) * 32 + q * 8;
            ah[t] = *(const short8*)(wohi + off);
            al[t] = *(const short8*)(wolo + off);
        }
#pragma unroll
        for (int t = 0; t < 2; ++t) {
            acc[t] = __builtin_amdgcn_mfma_f32_16x16x32_bf16(ah[t], bh.s, acc[t], 0, 0, 0);
            acc[t] = __builtin_amdgcn_mfma_f32_16x16x32_bf16(ah[t], bl.s, acc[t], 0, 0, 0);
            acc[t] = __builtin_amdgcn_mfma_f32_16x16x32_bf16(al[t], bh.s, acc[t], 0, 0, 0);
        }
    }

    const int p = y * 64 + xg;
    float* ob = om4 + (size_t)(kg * 2 + b) * 27 * HWPIX;
#pragma unroll
    for (int t = 0; t < 2; ++t) {
#pragma unroll
        for (int r = 0; r < 4; ++r) {
            int co = t * 16 + q * 4 + r;
            if (co < 27) ob[co * HWPIX + p] = acc[t][r];
        }
    }
}

// ---------------------------------------------------------------------------
// dcn: fused sampling + bf16x3 MFMA. Block = 256 co x 32 px, kg splits cb.
// Prologue sums the 4 om partials + bias. V rows padded to VSTR=40 shorts.
// ---------------------------------------------------------------------------
__global__ __launch_bounds__(256) void dcn_mfma_kernel(
    const float* __restrict__ xT,              // [2][4096][256]
    const float* __restrict__ om4,             // [4][2][27][4096]
    const unsigned short* __restrict__ whi,
    const unsigned short* __restrict__ wlo,
    const float* __restrict__ bom,             // [27]
    const float* __restrict__ bdcn,            // [256]
    float* __restrict__ out)                   // [2][256][4096] pre-zeroed
{
    const int tid = threadIdx.x;
    const int y   = blockIdx.x >> 1;
    const int xh  = blockIdx.x & 1;
    const int kg  = blockIdx.y;                // 0..1 channel halves
    const int b   = blockIdx.z;

    __shared__ float s_w00[288], s_w01[288], s_w10[288], s_w11[288];
    __shared__ int   s_i00[288], s_i01[288], s_i10[288], s_i11[288];
    __shared__ unsigned short Vhi[288 * VSTR];    // [k*32+px][ch], padded rows
    __shared__ unsigned short Vlo[288 * VSTR];

    // ---- prologue: sum om partials + bias; bilinear weights + indices ----
    for (int idx = tid; idx < 288; idx += 256) {
        int k   = idx >> 5;
        int pxl = idx & 31;
        int xg  = xh * 32 + pxl;
        int p   = y * 64 + xg;
        float dy = bom[2 * k], dx = bom[2 * k + 1], mm = bom[18 + k];
#pragma unroll
        for (int g = 0; g < 4; ++g) {
            const float* ob = om4 + (size_t)(g * 2 + b) * 27 * HWPIX;
            dy += ob[(2 * k) * HWPIX + p];
            dx += ob[(2 * k + 1) * HWPIX + p];
            mm += ob[(18 + k) * HWPIX + p];
        }
        float ys = (float)(y  - 1 + (k / 3)) + dy;
        float xs = (float)(xg - 1 + (k % 3)) + dx;
        float y0f = floorf(ys), x0f = floorf(xs);
        int y0 = (int)y0f, x0 = (int)x0f;
        float ly = ys - y0f, lx = xs - x0f;
        float m  = 1.0f / (1.0f + expf(-mm));
        bool yv0 = ((unsigned)y0 < 64u), yv1 = ((unsigned)(y0 + 1) < 64u);
        bool xv0 = ((unsigned)x0 < 64u), xv1 = ((unsigned)(x0 + 1) < 64u);
        float w00 = (1.0f - ly) * (1.0f - lx) * m;
        float w01 = (1.0f - ly) * lx * m;
        float w10 = ly * (1.0f - lx) * m;
        float w11 = ly * lx * m;
        int i00 = y0 * 64 + x0;
        s_w00[idx] = (yv0 && xv0) ? w00 : 0.0f;  s_i00[idx] = (yv0 && xv0) ? i00      : 0;
        s_w01[idx] = (yv0 && xv1) ? w01 : 0.0f;  s_i01[idx] = (yv0 && xv1) ? i00 + 1  : 0;
        s_w10[idx] = (yv1 && xv0) ? w10 : 0.0f;  s_i10[idx] = (yv1 && xv0) ? i00 + 64 : 0;
        s_w11[idx] = (yv1 && xv1) ? w11 : 0.0f;  s_i11[idx] = (yv1 && xv1) ? i00 + 65 : 0;
    }
    __syncthreads();

    const int w    = tid >> 6;
    const int lane = tid & 63;
    const int l15  = lane & 15;
    const int q    = lane >> 4;

    const int cg  = tid & 7;       // 4 channels each
    const int spx = tid >> 3;      // 0..31

    float4v acc[4][2];
#pragma unroll
    for (int t = 0; t < 4; ++t)
#pragma unroll
        for (int p = 0; p < 2; ++p) acc[t][p] = (float4v)0.0f;

    const float* xb = xT + ((size_t)b << 12) * 256;

    for (int cbl = 0; cbl < 4; ++cbl) {
        const int cb = kg * 4 + cbl;

        // ---- stage 9 taps x 32 px x 32 ch ----
        {
            const float* xc = xb + cb * 32 + cg * 4;
#pragma unroll 3
            for (int k = 0; k < 9; ++k) {
                int cidx = k * 32 + spx;
                float w00 = s_w00[cidx], w01 = s_w01[cidx];
                float w10 = s_w10[cidx], w11 = s_w11[cidx];
                int i00 = s_i00[cidx], i01 = s_i01[cidx];
                int i10 = s_i10[cidx], i11 = s_i11[cidx];
                float4 v00 = *(const float4*)(xc + (size_t)i00 * 256);
                float4 v01 = *(const float4*)(xc + (size_t)i01 * 256);
                float4 v10 = *(const float4*)(xc + (size_t)i10 * 256);
                float4 v11 = *(const float4*)(xc + (size_t)i11 * 256);
                float val[4];
                val[0] = w00 * v00.x + w01 * v01.x + w10 * v10.x + w11 * v11.x;
                val[1] = w00 * v00.y + w01 * v01.y + w10 * v10.y + w11 * v11.y;
                val[2] = w00 * v00.z + w01 * v01.z + w10 * v10.z + w11 * v11.z;
                val[3] = w00 * v00.w + w01 * v01.w + w10 * v10.w + w11 * v11.w;
                unsigned short h[4], l[4];
#pragma unroll
                for (int j = 0; j < 4; ++j) {
                    h[j] = f2bf(val[j]);
                    l[j] = f2bf_trunc(val[j] - bf2f(h[j]));
                }
                uint2 hv = make_uint2((unsigned)h[0] | ((unsigned)h[1] << 16),
                                      (unsigned)h[2] | ((unsigned)h[3] << 16));
                uint2 lv = make_uint2((unsigned)l[0] | ((unsigned)l[1] << 16),
                                      (unsigned)l[2] | ((unsigned)l[3] << 16));
                int vofs = (k * 32 + spx) * VSTR + cg * 4;
                *(uint2*)&Vhi[vofs] = hv;
                *(uint2*)&Vlo[vofs] = lv;
            }
        }
        __syncthreads();

        // ---- 9 barrier-free MFMA chunks ----
        for (int k = 0; k < 9; ++k) {
            const int kcb = k * 8 + cb;
            short8 ah[4], al[4];
#pragma unroll
            for (int t = 0; t < 4; ++t) {
                size_t off = ((size_t)kcb * 256 + w * 64 + t * 16 + l15) * 32 + q * 8;
                ah[t] = *(const short8*)(whi + off);
                al[t] = *(const short8*)(wlo + off);
            }
            short8 bh[2], bl[2];
#pragma unroll
            for (int p = 0; p < 2; ++p) {
                int vofs = (k * 32 + p * 16 + l15) * VSTR + q * 8;
                bh[p] = *(const short8*)&Vhi[vofs];
                bl[p] = *(const short8*)&Vlo[vofs];
            }
#pragma unroll
            for (int t = 0; t < 4; ++t) {
#pragma unroll
                for (int p = 0; p < 2; ++p) {
                    acc[t][p] = __builtin_amdgcn_mfma_f32_16x16x32_bf16(ah[t], bh[p], acc[t][p], 0, 0, 0);
                    acc[t][p] = __builtin_amdgcn_mfma_f32_16x16x32_bf16(ah[t], bl[p], acc[t][p], 0, 0, 0);
                    acc[t][p] = __builtin_amdgcn_mfma_f32_16x16x32_bf16(al[t], bh[p], acc[t][p], 0, 0, 0);
                }
            }
        }
        __syncthreads();
    }

    // ---- epilogue: atomic accumulate (kg partials); kg0 adds bias ----
#pragma unroll
    for (int t = 0; t < 4; ++t) {
#pragma unroll
        for (int r = 0; r < 4; ++r) {
            int co = w * 64 + t * 16 + q * 4 + r;
            float bias = (kg == 0) ? bdcn[co] : 0.0f;
#pragma unroll
            for (int p = 0; p < 2; ++p) {
                int px = xh * 32 + p * 16 + l15;
                atomicAdd(&out[(((size_t)b * COUT + co) << 12) + y * 64 + px],
                          acc[t][p][r] + bias);
            }
        }
    }
}

// ---------------------------------------------------------------------------
extern "C" void kernel_launch(void* const* d_in, const int* in_sizes, int n_in,
                              void* d_out, int out_size, void* d_ws, size_t ws_size,
                              hipStream_t stream)
{
    const float* x    = (const float*)d_in[0];
    const float* feat = (const float*)d_in[1];
    const float* wom  = (const float*)d_in[2];
    const float* bom  = (const float*)d_in[3];
    const float* wdcn = (const float*)d_in[4];
    const float* bdcn = (const float*)d_in[5];
    float* out = (float*)d_out;

    // workspace layout
    float* om4           = (float*)d_ws;                         // 4*2*27*4096
    unsigned short* whi  = (unsigned short*)(om4 + 4 * 2 * 27 * HWPIX);
    unsigned short* wlo  = whi + (size_t)CKTOT * 256;
    unsigned short* wohi = wlo + (size_t)CKTOT * 256;
    unsigned short* wolo = wohi + 73728;
    float* xT            = (float*)(wolo + 73728);               // 2*4096*256
    float* featTp        = xT + (size_t)2 * HWPIX * 256;         // 2*4356*256

    prep_kernel<<<8996, 256, 0, stream>>>(x, feat, wdcn, wom, xT, featTp,
                                          whi, wlo, wohi, wolo, out);

    dim3 gco(64, 4, 2);
    conv_om_mfma_kernel<<<gco, 256, 0, stream>>>(featTp, wohi, wolo, om4);

    dim3 grid(128, 2, 2);
    dcn_mfma_kernel<<<grid, 256, 0, stream>>>(xT, om4, whi, wlo, bom, bdcn, out);
}

// Round 6
// 153.314 us; speedup vs baseline: 4.9352x; 1.0379x over previous
//
#include <hip/hip_runtime.h>
#include <math.h>

#define BATCH 2
#define CIN   256
#define COUT  256
#define COFF  256
#define HWPIX 4096
#define CKTOT 2304
#define VSTR  40            // V row stride in shorts (80 B; 20 words mod 32 -> 2-way, free)
#define PH    66            // padded feat spatial dim
#define PHW   4356          // 66*66

typedef __attribute__((ext_vector_type(8))) short short8;
typedef __attribute__((ext_vector_type(4))) float float4v;

__device__ __forceinline__ unsigned short f2bf(float f) {
    unsigned u = __float_as_uint(f);
    unsigned r = (u + 0x7FFFu + ((u >> 16) & 1u)) >> 16;   // RNE
    return (unsigned short)r;
}
__device__ __forceinline__ unsigned short f2bf_trunc(float f) {
    return (unsigned short)(__float_as_uint(f) >> 16);
}
__device__ __forceinline__ float bf2f(unsigned short h) {
    return __uint_as_float(((unsigned)h) << 16);
}

// ---------------------------------------------------------------------------
// prep: ONE kernel, blockIdx regions:
//   [0,2048)      x -> xT (NHWC)
//   [2048,4096)   feat -> featTp (NHWC, zero-padded 66x66)
//   [4096,6400)   wpack   (w_dcn -> whi only; A-frag layout)
//   [6400,6688)   wpack_om(w_offset_mask -> wohi/wolo, M=32 padded)
//   [6688,7208)   zero featTp borders (BOTH batches — r5 bug fixed)
// ---------------------------------------------------------------------------
__global__ __launch_bounds__(256) void prep_kernel(
    const float* __restrict__ x, const float* __restrict__ feat,
    const float* __restrict__ wdcn, const float* __restrict__ wom,
    float* __restrict__ xT, float* __restrict__ featTp,
    unsigned short* __restrict__ whi,
    unsigned short* __restrict__ wohi, unsigned short* __restrict__ wolo)
{
    const int bid = blockIdx.x;
    const int tid = threadIdx.x;

    if (bid < 4096) {
        const bool isx = bid < 2048;
        const int lb = isx ? bid : bid - 2048;
        const int b  = lb >> 10;
        const int r  = lb & 1023;
        const int pt = r >> 3;       // 128 px tiles of 32
        const int ct = r & 7;        // 8 ch tiles of 32
        __shared__ float t[32][33];
        const int tx = tid & 31, ty = tid >> 5;
        const float* src = isx ? x : feat;
        const float* sb = src + ((size_t)b * 256 + ct * 32) * HWPIX + pt * 32;
#pragma unroll
        for (int i = ty; i < 32; i += 8)
            t[i][tx] = sb[(size_t)i * HWPIX + tx];
        __syncthreads();
        if (isx) {
            float* ob = xT + ((size_t)b * HWPIX + pt * 32) * 256 + ct * 32;
#pragma unroll
            for (int i = ty; i < 32; i += 8)
                ob[(size_t)i * 256 + tx] = t[tx][i];
        } else {
#pragma unroll
            for (int i = ty; i < 32; i += 8) {
                int p = pt * 32 + i;
                int row = (p >> 6) + 1, col = (p & 63) + 1;
                featTp[((size_t)b * PHW + row * PH + col) * 256 + ct * 32 + tx] = t[tx][i];
            }
        }
    } else if (bid < 6400) {
        int gid = (bid - 4096) * 256 + tid;    // 0..589823
        int cc  = gid & 31;
        int co  = (gid >> 5) & 255;
        int kcb = gid >> 13;
        int k   = kcb >> 3;
        int cb  = kcb & 7;
        float w = wdcn[((size_t)co * 256 + cb * 32 + cc) * 9 + k];
        whi[gid] = f2bf(w);
    } else if (bid < 6688) {
        int gid = (bid - 6400) * 256 + tid;    // 0..73727
        int cc  = gid & 31;
        int co  = (gid >> 5) & 31;
        int kcb = gid >> 10;
        int k   = kcb >> 3;
        int cb  = kcb & 7;
        float w = 0.0f;
        if (co < 27) w = wom[(size_t)co * CKTOT + (cb * 32 + cc) * 9 + k];
        unsigned short hi = f2bf(w);
        wohi[gid] = hi;
        wolo[gid] = f2bf_trunc(w - bf2f(hi));
    } else {
        int idx = (bid - 6688) * 256 + tid;    // < 133120 = 2*260*256 exactly
        int b = idx / 66560;
        int r = idx - b * 66560;
        int pidx = r >> 8;                     // 0..259 border cells
        int c = r & 255;
        int row, col;
        if (pidx < 66)       { row = 0;           col = pidx; }
        else if (pidx < 132) { row = 65;          col = pidx - 66; }
        else if (pidx < 196) { row = pidx - 131;  col = 0; }
        else                 { row = pidx - 195;  col = 65; }
        featTp[((size_t)b * PHW + row * PH + col) * 256 + c] = 0.0f;
    }
}

// ---------------------------------------------------------------------------
// conv_om via MFMA bf16x3, branchless (padded featTp), no atomics:
// each kg writes its own partial plane om4[kg][b][27][4096].
// ---------------------------------------------------------------------------
__global__ __launch_bounds__(256) void conv_om_mfma_kernel(
    const float* __restrict__ featTp,          // [2][4356][256]
    const unsigned short* __restrict__ wohi,
    const unsigned short* __restrict__ wolo,
    float* __restrict__ om4)                   // [4][2][27][4096]
{
    const int y  = blockIdx.x;     // 0..63
    const int kg = blockIdx.y;     // 0..3
    const int b  = blockIdx.z;
    const int tid = threadIdx.x;
    const int wv  = tid >> 6;
    const int lane = tid & 63;
    const int l15 = lane & 15;
    const int q   = lane >> 4;
    const int xg  = wv * 16 + l15;

    float4v acc[2];
    acc[0] = (float4v)0.0f;
    acc[1] = (float4v)0.0f;

    const float* fb = featTp + (size_t)b * PHW * 256;

    for (int i = 0; i < 18; ++i) {
        int kcb = kg * 18 + i;
        int k  = kcb >> 3;
        int cb = kcb & 7;
        const float* src = fb + ((size_t)((y + k / 3) * PH + xg + k % 3)) * 256
                              + cb * 32 + q * 8;
        float4 f0 = *(const float4*)src;
        float4 f1 = *(const float4*)(src + 4);
        float v[8] = {f0.x, f0.y, f0.z, f0.w, f1.x, f1.y, f1.z, f1.w};
        union { short8 s; unsigned u[4]; } bh, bl;
#pragma unroll
        for (int j = 0; j < 4; ++j) {
            unsigned short h0 = f2bf(v[2 * j]);
            unsigned short h1 = f2bf(v[2 * j + 1]);
            unsigned short l0 = f2bf_trunc(v[2 * j]     - bf2f(h0));
            unsigned short l1 = f2bf_trunc(v[2 * j + 1] - bf2f(h1));
            bh.u[j] = (unsigned)h0 | ((unsigned)h1 << 16);
            bl.u[j] = (unsigned)l0 | ((unsigned)l1 << 16);
        }
        short8 ah[2], al[2];
#pragma unroll
        for (int t = 0; t < 2; ++t) {
            size_t off = ((size_t)kcb * 32 + t * 16 + l15) * 32 + q * 8;
            ah[t] = *(const short8*)(wohi + off);
            al[t] = *(const short8*)(wolo + off);
        }
#pragma unroll
        for (int t = 0; t < 2; ++t) {
            acc[t] = __builtin_amdgcn_mfma_f32_16x16x32_bf16(ah[t], bh.s, acc[t], 0, 0, 0);
            acc[t] = __builtin_amdgcn_mfma_f32_16x16x32_bf16(ah[t], bl.s, acc[t], 0, 0, 0);
            acc[t] = __builtin_amdgcn_mfma_f32_16x16x32_bf16(al[t], bh.s, acc[t], 0, 0, 0);
        }
    }

    const int p = y * 64 + xg;
    float* ob = om4 + (size_t)(kg * 2 + b) * 27 * HWPIX;
#pragma unroll
    for (int t = 0; t < 2; ++t) {
#pragma unroll
        for (int r = 0; r < 4; ++r) {
            int co = t * 16 + q * 4 + r;
            if (co < 27) ob[co * HWPIX + p] = acc[t][r];
        }
    }
}

// ---------------------------------------------------------------------------
// dcn v4: fused sampling + MFMA (ah*bh + ah*bl). Full K per block, NO atomics.
// Block = 128 co x 16 px; grid (256 y*xq, 2 co-halves, 2 b) = 1024 blocks
// -> ~4 resident blocks/CU (LDS 28 KB), phase-offset blocks hide barriers.
// ---------------------------------------------------------------------------
__global__ __launch_bounds__(256, 4) void dcn_mfma_kernel(
    const float* __restrict__ xT,              // [2][4096][256]
    const float* __restrict__ om4,             // [4][2][27][4096]
    const unsigned short* __restrict__ whi,    // [72][256][32] bf16 hi
    const float* __restrict__ bom,             // [27]
    const float* __restrict__ bdcn,            // [256]
    float* __restrict__ out)                   // [2][256][4096]
{
    const int tid = threadIdx.x;
    const int y   = blockIdx.x >> 2;           // 0..63
    const int xq  = blockIdx.x & 3;            // 0..3 (16-px quarters)
    const int cog = blockIdx.y;                // 0..1 (co halves)
    const int b   = blockIdx.z;

    __shared__ float4 s_wt[144];               // w00,w01,w10,w11 (masked)
    __shared__ int4   s_ix[144];               // i00,i01,i10,i11 (clamped)
    __shared__ unsigned short Vhi[144 * VSTR]; // [k*16+px][ch], padded rows
    __shared__ unsigned short Vlo[144 * VSTR];

    // ---- prologue: sum om partials + bias; bilinear weights + indices ----
    if (tid < 144) {
        int k   = tid >> 4;
        int pxl = tid & 15;
        int xg  = xq * 16 + pxl;
        int p   = y * 64 + xg;
        float dy = bom[2 * k], dx = bom[2 * k + 1], mm = bom[18 + k];
#pragma unroll
        for (int g = 0; g < 4; ++g) {
            const float* ob = om4 + (size_t)(g * 2 + b) * 27 * HWPIX;
            dy += ob[(2 * k) * HWPIX + p];
            dx += ob[(2 * k + 1) * HWPIX + p];
            mm += ob[(18 + k) * HWPIX + p];
        }
        float ys = (float)(y  - 1 + (k / 3)) + dy;
        float xs = (float)(xg - 1 + (k % 3)) + dx;
        float y0f = floorf(ys), x0f = floorf(xs);
        int y0 = (int)y0f, x0 = (int)x0f;
        float ly = ys - y0f, lx = xs - x0f;
        float m  = 1.0f / (1.0f + expf(-mm));
        bool yv0 = ((unsigned)y0 < 64u), yv1 = ((unsigned)(y0 + 1) < 64u);
        bool xv0 = ((unsigned)x0 < 64u), xv1 = ((unsigned)(x0 + 1) < 64u);
        int i00 = y0 * 64 + x0;
        float4 wt;
        int4 ix;
        wt.x = (yv0 && xv0) ? (1.0f - ly) * (1.0f - lx) * m : 0.0f;
        wt.y = (yv0 && xv1) ? (1.0f - ly) * lx * m          : 0.0f;
        wt.z = (yv1 && xv0) ? ly * (1.0f - lx) * m          : 0.0f;
        wt.w = (yv1 && xv1) ? ly * lx * m                   : 0.0f;
        ix.x = (yv0 && xv0) ? i00      : 0;
        ix.y = (yv0 && xv1) ? i00 + 1  : 0;
        ix.z = (yv1 && xv0) ? i00 + 64 : 0;
        ix.w = (yv1 && xv1) ? i00 + 65 : 0;
        s_wt[tid] = wt;
        s_ix[tid] = ix;
    }
    __syncthreads();

    const int w    = tid >> 6;     // wave -> co base cog*128 + w*32
    const int lane = tid & 63;
    const int l15  = lane & 15;
    const int q    = lane >> 4;

    // staging map: cg = tid&7 (4 ch), px = (tid>>3)&15, half = tid>>7
    const int cg   = tid & 7;
    const int spx  = (tid >> 3) & 15;
    const int half = tid >> 7;

    float4v acc[2];
    acc[0] = (float4v)0.0f;
    acc[1] = (float4v)0.0f;

    const float* xb = xT + ((size_t)b << 12) * 256;

    for (int cb = 0; cb < 8; ++cb) {
        // ---- stage: taps {half, half+2, ...} x 16 px x 32 ch ----
        {
            const float* xc = xb + cb * 32 + cg * 4;
#pragma unroll
            for (int j = 0; j < 5; ++j) {
                int k = 2 * j + half;
                if (k > 8) break;
                int cidx = k * 16 + spx;
                float4 wt = s_wt[cidx];
                int4   ix = s_ix[cidx];
                float4 v00 = *(const float4*)(xc + (size_t)ix.x * 256);
                float4 v01 = *(const float4*)(xc + (size_t)ix.y * 256);
                float4 v10 = *(const float4*)(xc + (size_t)ix.z * 256);
                float4 v11 = *(const float4*)(xc + (size_t)ix.w * 256);
                float val[4];
                val[0] = wt.x * v00.x + wt.y * v01.x + wt.z * v10.x + wt.w * v11.x;
                val[1] = wt.x * v00.y + wt.y * v01.y + wt.z * v10.y + wt.w * v11.y;
                val[2] = wt.x * v00.z + wt.y * v01.z + wt.z * v10.z + wt.w * v11.z;
                val[3] = wt.x * v00.w + wt.y * v01.w + wt.z * v10.w + wt.w * v11.w;
                unsigned short h[4], l[4];
#pragma unroll
                for (int jj = 0; jj < 4; ++jj) {
                    h[jj] = f2bf(val[jj]);
                    l[jj] = f2bf_trunc(val[jj] - bf2f(h[jj]));
                }
                uint2 hv = make_uint2((unsigned)h[0] | ((unsigned)h[1] << 16),
                                      (unsigned)h[2] | ((unsigned)h[3] << 16));
                uint2 lv = make_uint2((unsigned)l[0] | ((unsigned)l[1] << 16),
                                      (unsigned)l[2] | ((unsigned)l[3] << 16));
                int vofs = cidx * VSTR + cg * 4;
                *(uint2*)&Vhi[vofs] = hv;
                *(uint2*)&Vlo[vofs] = lv;
            }
        }
        __syncthreads();

        // ---- 9 barrier-free MFMA chunks ----
        for (int k = 0; k < 9; ++k) {
            const int kcb = k * 8 + cb;
            short8 ah[2];
#pragma unroll
            for (int t = 0; t < 2; ++t) {
                int co = cog * 128 + w * 32 + t * 16 + l15;
                ah[t] = *(const short8*)(whi + ((size_t)kcb * 256 + co) * 32 + q * 8);
            }
            int vbase = (k * 16 + l15) * VSTR + q * 8;
            short8 bh = *(const short8*)&Vhi[vbase];
            short8 bl = *(const short8*)&Vlo[vbase];
#pragma unroll
            for (int t = 0; t < 2; ++t) {
                acc[t] = __builtin_amdgcn_mfma_f32_16x16x32_bf16(ah[t], bh, acc[t], 0, 0, 0);
                acc[t] = __builtin_amdgcn_mfma_f32_16x16x32_bf16(ah[t], bl, acc[t], 0, 0, 0);
            }
        }
        __syncthreads();
    }

    // ---- epilogue: plain stores (D: row co = q*4+r, col px = l15) ----
#pragma unroll
    for (int t = 0; t < 2; ++t) {
#pragma unroll
        for (int r = 0; r < 4; ++r) {
            int co = cog * 128 + w * 32 + t * 16 + q * 4 + r;
            out[(((size_t)b * COUT + co) << 12) + y * 64 + xq * 16 + l15]
                = acc[t][r] + bdcn[co];
        }
    }
}

// ---------------------------------------------------------------------------
extern "C" void kernel_launch(void* const* d_in, const int* in_sizes, int n_in,
                              void* d_out, int out_size, void* d_ws, size_t ws_size,
                              hipStream_t stream)
{
    const float* x    = (const float*)d_in[0];
    const float* feat = (const float*)d_in[1];
    const float* wom  = (const float*)d_in[2];
    const float* bom  = (const float*)d_in[3];
    const float* wdcn = (const float*)d_in[4];
    const float* bdcn = (const float*)d_in[5];
    float* out = (float*)d_out;

    // workspace layout
    float* om4           = (float*)d_ws;                         // 4*2*27*4096
    unsigned short* whi  = (unsigned short*)(om4 + 4 * 2 * 27 * HWPIX);
    unsigned short* wohi = whi + (size_t)CKTOT * 256;
    unsigned short* wolo = wohi + 73728;
    float* xT            = (float*)(wolo + 73728);               // 2*4096*256
    float* featTp        = xT + (size_t)2 * HWPIX * 256;         // 2*4356*256

    prep_kernel<<<7208, 256, 0, stream>>>(x, feat, wdcn, wom, xT, featTp,
                                          whi, wohi, wolo);

    dim3 gco(64, 4, 2);
    conv_om_mfma_kernel<<<gco, 256, 0, stream>>>(featTp, wohi, wolo, om4);

    dim3 grid(256, 2, 2);
    dcn_mfma_kernel<<<grid, 256, 0, stream>>>(xT, om4, whi, bom, bdcn, out);
}